// Round 1
// baseline (224.538 us; speedup 1.0000x reference)
//
#include <hip/hip_runtime.h>

// Speech MSA with dynamic windows — fp32 baseline.
// B=4, T=4160 (W=64 word tokens + F=4096 frames), E=256, H=4, D=64,
// LOCAL_SIZE=15 (pad 7), chunk = F/W = 64, n = B*H = 16.
//
// Pipeline (4 kernels, one stream):
//  1. qkv_gemm : qkv = x[:,64:] @ W_qkv + b_qkv, scattered to head layout
//                Q scaled by 0.125. (M=16384, N=768, K=256)
//  2. expa     : expa[n,f,:] = sum_w wm[b,w,f] * x[b,w,h*64:...]  (general einsum)
//  3. attn     : per (n, window): 64 frames; s0 = Q.expa (chunk softmax over 64),
//                s1..15 = Q.K[f-7..f+7] (softmax over 15 incl. zero-pad scores);
//                out_fea = w0*expa + sum_j wj*V[f-7+j]
//  4. out_gemm : out = concat(x[:, :64], out_fea) @ W_out + b_out (A-row gather)

#define QN 4194304ull  // 16 * 4096 * 64 floats per head-layout buffer

// ---------------------------------------------------------------- K1: QKV gemm
// BM=128, BN=64, BK=16, 256 threads, 8x4 microtile.
__global__ __launch_bounds__(256) void qkv_gemm(
    const float* __restrict__ x, const float* __restrict__ Wq,
    const float* __restrict__ bq,
    float* __restrict__ Qb, float* __restrict__ Kb, float* __restrict__ Vb) {
  __shared__ float As[16][132];  // transposed A tile, pad->row 528B (16B aligned)
  __shared__ float Bs[16][64];
  const int tid = threadIdx.x;
  const int m0 = blockIdx.x * 128;
  const int n0 = blockIdx.y * 64;

  const int li = tid >> 1;          // A load row 0..127
  const int lk = (tid & 1) * 8;     // A load k offset {0,8}
  const int mr = m0 + li;
  const int ab = mr >> 12, af = mr & 4095;          // b, frame
  const float* xrow = x + ((size_t)(ab * 4160 + 64 + af)) * 256;

  const int wk = tid >> 4;          // B load k row 0..15
  const int wj = (tid & 15) * 4;    // B load col
  const float* wrow = Wq + (size_t)wk * 768 + n0 + wj;

  const int ty = tid >> 4, tx = tid & 15;
  float acc[8][4] = {};

  for (int k0 = 0; k0 < 256; k0 += 16) {
    float4 a0 = *(const float4*)(xrow + k0 + lk);
    float4 a1 = *(const float4*)(xrow + k0 + lk + 4);
    float4 bv = *(const float4*)(wrow + (size_t)k0 * 768);
    __syncthreads();
    As[lk + 0][li] = a0.x; As[lk + 1][li] = a0.y;
    As[lk + 2][li] = a0.z; As[lk + 3][li] = a0.w;
    As[lk + 4][li] = a1.x; As[lk + 5][li] = a1.y;
    As[lk + 6][li] = a1.z; As[lk + 7][li] = a1.w;
    *(float4*)&Bs[wk][wj] = bv;
    __syncthreads();
#pragma unroll
    for (int kk = 0; kk < 16; ++kk) {
      float4 av0 = *(const float4*)&As[kk][ty * 8];
      float4 av1 = *(const float4*)&As[kk][ty * 8 + 4];
      float4 bv0 = *(const float4*)&Bs[kk][tx * 4];
      float a[8] = {av0.x, av0.y, av0.z, av0.w, av1.x, av1.y, av1.z, av1.w};
      float bb[4] = {bv0.x, bv0.y, bv0.z, bv0.w};
#pragma unroll
      for (int ii = 0; ii < 8; ++ii)
#pragma unroll
        for (int jj = 0; jj < 4; ++jj)
          acc[ii][jj] = fmaf(a[ii], bb[jj], acc[ii][jj]);
    }
  }

  // epilogue: c-range [n0+tx*4, +4) lies inside one (which, h) 64-block
  const int c = n0 + tx * 4;
  const int which = c >> 8;
  const int e = c & 255;
  const int h = e >> 6, d = e & 63;
  float* dst = (which == 0) ? Qb : (which == 1) ? Kb : Vb;
  const float sc = (which == 0) ? 0.125f : 1.0f;
  float4 bias = *(const float4*)(bq + c);
#pragma unroll
  for (int ii = 0; ii < 8; ++ii) {
    int m2 = m0 + ty * 8 + ii;
    int b2 = m2 >> 12, f2 = m2 & 4095;
    float4 v;
    v.x = (acc[ii][0] + bias.x) * sc;
    v.y = (acc[ii][1] + bias.y) * sc;
    v.z = (acc[ii][2] + bias.z) * sc;
    v.w = (acc[ii][3] + bias.w) * sc;
    *(float4*)(dst + (((size_t)(b2 * 4 + h)) * 4096 + f2) * 64 + d) = v;
  }
}

// ---------------------------------------------------------------- K2: expa
// one block per (b,h,f-tile of 64): expa[n, f, d] = sum_w wm[b,w,f]*x[b,w,h*64+d]
__global__ __launch_bounds__(256) void expa_kernel(
    const float* __restrict__ x, const float* __restrict__ wm,
    float* __restrict__ ex) {
  __shared__ float Xs[64][68];  // [w][d]
  __shared__ float Ws[64][68];  // [w][f_local]
  const int tid = threadIdx.x;
  const int f0 = blockIdx.x * 64;
  const int bh = blockIdx.y;
  const int b = bh >> 2, h = bh & 3;
  {
    const int w = tid >> 2, c0 = (tid & 3) * 16;
    const float* xr = x + ((size_t)(b * 4160 + w)) * 256 + h * 64 + c0;
    const float* wr = wm + ((size_t)(b * 64 + w)) * 4096 + f0 + c0;
#pragma unroll
    for (int cc = 0; cc < 16; cc += 4) {
      *(float4*)&Xs[w][c0 + cc] = *(const float4*)(xr + cc);
      *(float4*)&Ws[w][c0 + cc] = *(const float4*)(wr + cc);
    }
  }
  __syncthreads();
  const int ty = tid >> 4, tx = tid & 15;
  float acc[4][4] = {};
  for (int w = 0; w < 64; ++w) {
    float4 a4 = *(const float4*)&Ws[w][ty * 4];
    float4 b4 = *(const float4*)&Xs[w][tx * 4];
    float a[4] = {a4.x, a4.y, a4.z, a4.w};
    float bb[4] = {b4.x, b4.y, b4.z, b4.w};
#pragma unroll
    for (int ii = 0; ii < 4; ++ii)
#pragma unroll
      for (int jj = 0; jj < 4; ++jj)
        acc[ii][jj] = fmaf(a[ii], bb[jj], acc[ii][jj]);
  }
#pragma unroll
  for (int ii = 0; ii < 4; ++ii) {
    int fi = f0 + ty * 4 + ii;
    float4 v = {acc[ii][0], acc[ii][1], acc[ii][2], acc[ii][3]};
    *(float4*)(ex + ((size_t)bh * 4096 + fi) * 64 + tx * 4) = v;
  }
}

// ---------------------------------------------------------------- K3: attention
// one block per (n, window w): 64 frames; thread quad (4 lanes) per frame,
// each lane owns 16 of the 64 dims.
__global__ __launch_bounds__(256) void attn_kernel(
    const float* __restrict__ Qb, const float* __restrict__ Kb,
    const float* __restrict__ Vb, const float* __restrict__ ex,
    float* __restrict__ of) {
  __shared__ float Ks[78][68];
  __shared__ float Vs[78][68];
  __shared__ float s0s[64];
  __shared__ float red[2];
  const int tid = threadIdx.x;
  const int w = blockIdx.x;   // window 0..63
  const int n = blockIdx.y;   // head-batch 0..15
  const int f0 = w * 64;

  // stage K/V rows f0-7 .. f0+70 (zero-padded at the ends)
  for (int idx = tid; idx < 78 * 16; idx += 256) {
    int r = idx >> 4, c = (idx & 15) * 4;
    int g = f0 - 7 + r;
    float4 kv = {0.f, 0.f, 0.f, 0.f}, vv = {0.f, 0.f, 0.f, 0.f};
    if (g >= 0 && g < 4096) {
      size_t base = ((size_t)n * 4096 + g) * 64 + c;
      kv = *(const float4*)(Kb + base);
      vv = *(const float4*)(Vb + base);
    }
    *(float4*)&Ks[r][c] = kv;
    *(float4*)&Vs[r][c] = vv;
  }
  __syncthreads();

  const int i = tid >> 2, q = tid & 3;   // frame-local, dim-quad
  const int f = f0 + i;
  const size_t qbase = ((size_t)n * 4096 + f) * 64 + q * 16;
  float4 q0 = *(const float4*)(Qb + qbase);
  float4 q1 = *(const float4*)(Qb + qbase + 4);
  float4 q2 = *(const float4*)(Qb + qbase + 8);
  float4 q3 = *(const float4*)(Qb + qbase + 12);
  float4 e0 = *(const float4*)(ex + qbase);
  float4 e1 = *(const float4*)(ex + qbase + 4);
  float4 e2 = *(const float4*)(ex + qbase + 8);
  float4 e3 = *(const float4*)(ex + qbase + 12);

  // s0 = Q . expa (partial over this lane's 16 dims)
  float s0 = q0.x * e0.x + q0.y * e0.y + q0.z * e0.z + q0.w * e0.w +
             q1.x * e1.x + q1.y * e1.y + q1.z * e1.z + q1.w * e1.w +
             q2.x * e2.x + q2.y * e2.y + q2.z * e2.z + q2.w * e2.w +
             q3.x * e3.x + q3.y * e3.y + q3.z * e3.z + q3.w * e3.w;
  s0 += __shfl_xor(s0, 1);
  s0 += __shfl_xor(s0, 2);

  // local scores: K rows i+j (j=0..14) in the staged tile
  float sj[15];
#pragma unroll
  for (int j = 0; j < 15; ++j) {
    const float* kr = &Ks[i + j][q * 16];
    float4 k0 = *(const float4*)(kr);
    float4 k1 = *(const float4*)(kr + 4);
    float4 k2 = *(const float4*)(kr + 8);
    float4 k3 = *(const float4*)(kr + 12);
    float s = q0.x * k0.x + q0.y * k0.y + q0.z * k0.z + q0.w * k0.w +
              q1.x * k1.x + q1.y * k1.y + q1.z * k1.z + q1.w * k1.w +
              q2.x * k2.x + q2.y * k2.y + q2.z * k2.z + q2.w * k2.w +
              q3.x * k3.x + q3.y * k3.y + q3.z * k3.z + q3.w * k3.w;
    s += __shfl_xor(s, 1);
    s += __shfl_xor(s, 2);
    sj[j] = s;
  }

  // chunk softmax over the window's 64 frames (word-token weight)
  if (q == 0) s0s[i] = s0;
  __syncthreads();
  if (tid < 64) {
    float v = s0s[tid];
    float m = v;
    for (int o = 1; o < 64; o <<= 1) m = fmaxf(m, __shfl_xor(m, o));
    float ee = expf(v - m);
    float s = ee;
    for (int o = 1; o < 64; o <<= 1) s += __shfl_xor(s, o);
    if (tid == 0) { red[0] = m; red[1] = s; }
  }
  __syncthreads();
  const float wt = expf(s0 - red[0]) / red[1];

  // local softmax over 15 (zero-pad scores included, matching reference)
  float mx = sj[0];
#pragma unroll
  for (int j = 1; j < 15; ++j) mx = fmaxf(mx, sj[j]);
  float pj[15], den = 0.f;
#pragma unroll
  for (int j = 0; j < 15; ++j) { pj[j] = expf(sj[j] - mx); den += pj[j]; }
  const float inv = 1.0f / den;

  // output: wt*expa + sum_j wj * V[f-7+j]
  float o[16] = {wt * e0.x, wt * e0.y, wt * e0.z, wt * e0.w,
                 wt * e1.x, wt * e1.y, wt * e1.z, wt * e1.w,
                 wt * e2.x, wt * e2.y, wt * e2.z, wt * e2.w,
                 wt * e3.x, wt * e3.y, wt * e3.z, wt * e3.w};
#pragma unroll
  for (int j = 0; j < 15; ++j) {
    float wj = pj[j] * inv;
    const float* vr = &Vs[i + j][q * 16];
#pragma unroll
    for (int dd = 0; dd < 16; ++dd) o[dd] = fmaf(wj, vr[dd], o[dd]);
  }
  float4 o0 = {o[0], o[1], o[2], o[3]};
  float4 o1 = {o[4], o[5], o[6], o[7]};
  float4 o2 = {o[8], o[9], o[10], o[11]};
  float4 o3 = {o[12], o[13], o[14], o[15]};
  *(float4*)(of + qbase) = o0;
  *(float4*)(of + qbase + 4) = o1;
  *(float4*)(of + qbase + 8) = o2;
  *(float4*)(of + qbase + 12) = o3;
}

// ---------------------------------------------------------------- K4: out proj
// BM=128, BN=64, BK=16; A rows gathered: t<64 -> x row, else out_fea head layout
__global__ __launch_bounds__(256) void out_gemm(
    const float* __restrict__ x, const float* __restrict__ of,
    const float* __restrict__ Wo, const float* __restrict__ bo,
    float* __restrict__ out) {
  __shared__ float As[16][132];
  __shared__ float Bs[16][64];
  const int tid = threadIdx.x;
  const int m0 = blockIdx.x * 128;
  const int n0 = blockIdx.y * 64;

  const int li = tid >> 1, lk = (tid & 1) * 8;
  const int mr = m0 + li;
  const int ab = mr / 4160, at = mr % 4160;
  const bool useX = (at < 64);

  const int wk = tid >> 4, wj = (tid & 15) * 4;
  const int ty = tid >> 4, tx = tid & 15;
  float acc[8][4] = {};

  for (int k0 = 0; k0 < 256; k0 += 16) {
    const int k = k0 + lk;
    float4 a0, a1;
    if (useX) {
      const float* p = x + ((size_t)(ab * 4160 + at)) * 256 + k;
      a0 = *(const float4*)p;
      a1 = *(const float4*)(p + 4);
    } else {
      const int h = k >> 6, d = k & 63;  // 8 consecutive k stay in one h
      const float* p = of + (((size_t)(ab * 4 + h)) * 4096 + (at - 64)) * 64 + d;
      a0 = *(const float4*)p;
      a1 = *(const float4*)(p + 4);
    }
    float4 bv = *(const float4*)(Wo + (size_t)(k0 + wk) * 256 + n0 + wj);
    __syncthreads();
    As[lk + 0][li] = a0.x; As[lk + 1][li] = a0.y;
    As[lk + 2][li] = a0.z; As[lk + 3][li] = a0.w;
    As[lk + 4][li] = a1.x; As[lk + 5][li] = a1.y;
    As[lk + 6][li] = a1.z; As[lk + 7][li] = a1.w;
    *(float4*)&Bs[wk][wj] = bv;
    __syncthreads();
#pragma unroll
    for (int kk = 0; kk < 16; ++kk) {
      float4 av0 = *(const float4*)&As[kk][ty * 8];
      float4 av1 = *(const float4*)&As[kk][ty * 8 + 4];
      float4 bv0 = *(const float4*)&Bs[kk][tx * 4];
      float a[8] = {av0.x, av0.y, av0.z, av0.w, av1.x, av1.y, av1.z, av1.w};
      float bb[4] = {bv0.x, bv0.y, bv0.z, bv0.w};
#pragma unroll
      for (int ii = 0; ii < 8; ++ii)
#pragma unroll
        for (int jj = 0; jj < 4; ++jj)
          acc[ii][jj] = fmaf(a[ii], bb[jj], acc[ii][jj]);
    }
  }

  const int c = n0 + tx * 4;
  float4 bias = *(const float4*)(bo + c);
#pragma unroll
  for (int ii = 0; ii < 8; ++ii) {
    int m2 = m0 + ty * 8 + ii;
    float4 v;
    v.x = acc[ii][0] + bias.x;
    v.y = acc[ii][1] + bias.y;
    v.z = acc[ii][2] + bias.z;
    v.w = acc[ii][3] + bias.w;
    *(float4*)(out + (size_t)m2 * 256 + c) = v;
  }
}

// ---------------------------------------------------------------- launch
extern "C" void kernel_launch(void* const* d_in, const int* in_sizes, int n_in,
                              void* d_out, int out_size, void* d_ws, size_t ws_size,
                              hipStream_t stream) {
  const float* x  = (const float*)d_in[0];
  const float* wm = (const float*)d_in[1];
  const float* Wq = (const float*)d_in[2];
  const float* bq = (const float*)d_in[3];
  const float* Wo = (const float*)d_in[4];
  const float* bo = (const float*)d_in[5];
  float* out = (float*)d_out;
  float* ws = (float*)d_ws;

  float* Qb = ws;            // 16 x 4096 x 64 each
  float* Kb = ws + QN;
  float* Vb = ws + 2 * QN;
  float* EX = ws + 3 * QN;
  float* OF = ws + 4 * QN;   // total 5*QN*4 = 84 MB workspace

  qkv_gemm<<<dim3(128, 12), 256, 0, stream>>>(x, Wq, bq, Qb, Kb, Vb);
  expa_kernel<<<dim3(64, 16), 256, 0, stream>>>(x, wm, EX);
  attn_kernel<<<dim3(64, 16), 256, 0, stream>>>(Qb, Kb, Vb, EX, OF);
  out_gemm<<<dim3(130, 4), 256, 0, stream>>>(x, OF, Wo, bo, out);
}

// Round 2
// 178.437 us; speedup vs baseline: 1.2584x; 1.2584x over previous
//
#include <hip/hip_runtime.h>

// Speech MSA with dynamic windows.
// B=4, T=4160 (W=64 word tokens + F=4096 frames), E=256, H=4, D=64,
// LOCAL_SIZE=15 (pad 7), chunk = F/W = 64, n = B*H = 16.
//
// R1: both gemms moved to MFMA f32_32x32x16_f16 with fp32->f16 hi/lo split
// (3-product Markidis: hi*hi + hi*lo + lo*hi; error ~2^-22 rel, fp32-class).
// Pre-pass converts x and transposed weights to hi/lo f16; attention writes
// its output directly as hi/lo f16 for the out-projection.

#define QN 4194304ull          // 16 * 4096 * 64 elements (head-layout buffers)
#define XN 4259840             // 4 * 4160 * 256 elements (full x)

typedef _Float16 h8 __attribute__((ext_vector_type(8)));
typedef _Float16 h4 __attribute__((ext_vector_type(4)));
typedef float f32x16 __attribute__((ext_vector_type(16)));

// ------------------------------------------------------------- pre-convert x
__global__ __launch_bounds__(256) void conv_x(
    const float* __restrict__ x, _Float16* __restrict__ xh,
    _Float16* __restrict__ xl) {
  int i = blockIdx.x * 256 + threadIdx.x;   // one float4 per thread
  float4 v = ((const float4*)x)[i];
  _Float16 h0 = (_Float16)v.x, h1 = (_Float16)v.y;
  _Float16 h2 = (_Float16)v.z, h3 = (_Float16)v.w;
  h4 hh = {h0, h1, h2, h3};
  h4 ll = {(_Float16)(v.x - (float)h0), (_Float16)(v.y - (float)h1),
           (_Float16)(v.z - (float)h2), (_Float16)(v.w - (float)h3)};
  ((h4*)xh)[i] = hh;
  ((h4*)xl)[i] = ll;
}

// -------------------------------------- pre-convert weight, transposed [N][K]
// src is [K=256][N] fp32; dst_h/l are [N][256] f16.
__global__ __launch_bounds__(256) void conv_wT(
    const float* __restrict__ src, _Float16* __restrict__ dh,
    _Float16* __restrict__ dl, int N) {
  int o = blockIdx.x * 256 + threadIdx.x;
  int n = o >> 8, k = o & 255;
  float v = src[(size_t)k * N + n];
  _Float16 h = (_Float16)v;
  dh[o] = h;
  dl[o] = (_Float16)(v - (float)h);
}

// ---------------------------------------------------------------- K1: QKV gemm
// MFMA f16x3. M=16384 (frames), N=768, K=256. Block 128x64, 4 waves,
// wave = 2 M-tiles (32) x 1 N-tile (32). A staged in LDS (pad 40), B direct
// from L2-resident transposed weights.
__global__ __launch_bounds__(256) void qkv_mfma(
    const _Float16* __restrict__ xh, const _Float16* __restrict__ xl,
    const _Float16* __restrict__ wth, const _Float16* __restrict__ wtl,
    const float* __restrict__ bq,
    float* __restrict__ Qb, float* __restrict__ Kb, float* __restrict__ Vb) {
  __shared__ _Float16 Ah[128][40];   // pad 32->40: 80B rows, 16B-aligned frags,
  __shared__ _Float16 Al[128][40];   // bank starts 20m%32 spread over 8 slots
  const int tid = threadIdx.x;
  const int wave = tid >> 6, lane = tid & 63;
  const int ln = lane & 31, half = lane >> 5;
  const int mw = (wave & 1) * 64, nw = (wave >> 1) * 32;
  const int m0 = blockIdx.x * 128, n0 = blockIdx.y * 64;

  const int r = tid >> 1, seg = tid & 1;        // A staging: row, 16-f16 chunk
  const int grow = m0 + r;
  const size_t aoff =
      ((size_t)((grow >> 12) * 4160 + 64 + (grow & 4095))) * 256 + seg * 16;

  const _Float16* wp_h = wth + (size_t)(n0 + nw + ln) * 256 + half * 8;
  const _Float16* wp_l = wtl + (size_t)(n0 + nw + ln) * 256 + half * 8;

  f32x16 acc0 = {}, acc1 = {};

  for (int k0 = 0; k0 < 256; k0 += 32) {
    float4 gh0 = *(const float4*)(xh + aoff + k0);
    float4 gh1 = *(const float4*)(xh + aoff + k0 + 8);
    float4 gl0 = *(const float4*)(xl + aoff + k0);
    float4 gl1 = *(const float4*)(xl + aoff + k0 + 8);
    h8 bh0 = *(const h8*)(wp_h + k0);
    h8 bh1 = *(const h8*)(wp_h + k0 + 16);
    h8 bl0 = *(const h8*)(wp_l + k0);
    h8 bl1 = *(const h8*)(wp_l + k0 + 16);
    __syncthreads();
    *(float4*)&Ah[r][seg * 16] = gh0;
    *(float4*)&Ah[r][seg * 16 + 8] = gh1;
    *(float4*)&Al[r][seg * 16] = gl0;
    *(float4*)&Al[r][seg * 16 + 8] = gl1;
    __syncthreads();
#pragma unroll
    for (int ks = 0; ks < 2; ++ks) {
      const int kc = ks * 16 + half * 8;
      h8 a0h = *(const h8*)&Ah[mw + ln][kc];
      h8 a0l = *(const h8*)&Al[mw + ln][kc];
      h8 a1h = *(const h8*)&Ah[mw + 32 + ln][kc];
      h8 a1l = *(const h8*)&Al[mw + 32 + ln][kc];
      h8 bh = ks ? bh1 : bh0;
      h8 bl = ks ? bl1 : bl0;
      acc0 = __builtin_amdgcn_mfma_f32_32x32x16_f16(a0h, bh, acc0, 0, 0, 0);
      acc1 = __builtin_amdgcn_mfma_f32_32x32x16_f16(a1h, bh, acc1, 0, 0, 0);
      acc0 = __builtin_amdgcn_mfma_f32_32x32x16_f16(a0h, bl, acc0, 0, 0, 0);
      acc1 = __builtin_amdgcn_mfma_f32_32x32x16_f16(a1h, bl, acc1, 0, 0, 0);
      acc0 = __builtin_amdgcn_mfma_f32_32x32x16_f16(a0l, bh, acc0, 0, 0, 0);
      acc1 = __builtin_amdgcn_mfma_f32_32x32x16_f16(a1l, bh, acc1, 0, 0, 0);
    }
  }

  // epilogue: C/D layout col=lane&31, row=(reg&3)+8*(reg>>2)+4*(lane>>5)
  const int c = n0 + nw + ln;
  const int which = c >> 8, e = c & 255;
  const int h = e >> 6, d = e & 63;
  float* dst = (which == 0) ? Qb : (which == 1) ? Kb : Vb;
  const float sc = (which == 0) ? 0.125f : 1.0f;
  const float bias = bq[c];
#pragma unroll
  for (int t = 0; t < 2; ++t) {
    const int rb = m0 + mw + t * 32 + 4 * half;
#pragma unroll
    for (int reg = 0; reg < 16; ++reg) {
      float av = t ? acc1[reg] : acc0[reg];
      int rr = rb + (reg & 3) + 8 * (reg >> 2);
      int b2 = rr >> 12, f2 = rr & 4095;
      dst[(((size_t)(b2 * 4 + h)) * 4096 + f2) * 64 + d] = (av + bias) * sc;
    }
  }
}

// ---------------------------------------------------------------- K2: expa
__global__ __launch_bounds__(256) void expa_kernel(
    const float* __restrict__ x, const float* __restrict__ wm,
    float* __restrict__ ex) {
  __shared__ float Xs[64][68];
  __shared__ float Ws[64][68];
  const int tid = threadIdx.x;
  const int f0 = blockIdx.x * 64;
  const int bh = blockIdx.y;
  const int b = bh >> 2, h = bh & 3;
  {
    const int w = tid >> 2, c0 = (tid & 3) * 16;
    const float* xr = x + ((size_t)(b * 4160 + w)) * 256 + h * 64 + c0;
    const float* wr = wm + ((size_t)(b * 64 + w)) * 4096 + f0 + c0;
#pragma unroll
    for (int cc = 0; cc < 16; cc += 4) {
      *(float4*)&Xs[w][c0 + cc] = *(const float4*)(xr + cc);
      *(float4*)&Ws[w][c0 + cc] = *(const float4*)(wr + cc);
    }
  }
  __syncthreads();
  const int ty = tid >> 4, tx = tid & 15;
  float acc[4][4] = {};
  for (int w = 0; w < 64; ++w) {
    float4 a4 = *(const float4*)&Ws[w][ty * 4];
    float4 b4 = *(const float4*)&Xs[w][tx * 4];
    float a[4] = {a4.x, a4.y, a4.z, a4.w};
    float bb[4] = {b4.x, b4.y, b4.z, b4.w};
#pragma unroll
    for (int ii = 0; ii < 4; ++ii)
#pragma unroll
      for (int jj = 0; jj < 4; ++jj)
        acc[ii][jj] = fmaf(a[ii], bb[jj], acc[ii][jj]);
  }
#pragma unroll
  for (int ii = 0; ii < 4; ++ii) {
    int fi = f0 + ty * 4 + ii;
    float4 v = {acc[ii][0], acc[ii][1], acc[ii][2], acc[ii][3]};
    *(float4*)(ex + ((size_t)bh * 4096 + fi) * 64 + tx * 4) = v;
  }
}

// ---------------------------------------------------------------- K3: attention
// outputs hi/lo f16 (consumed by out_mfma)
__global__ __launch_bounds__(256) void attn_kernel(
    const float* __restrict__ Qb, const float* __restrict__ Kb,
    const float* __restrict__ Vb, const float* __restrict__ ex,
    _Float16* __restrict__ OFh, _Float16* __restrict__ OFl) {
  __shared__ float Ks[78][68];
  __shared__ float Vs[78][68];
  __shared__ float s0s[64];
  __shared__ float red[2];
  const int tid = threadIdx.x;
  const int w = blockIdx.x;
  const int n = blockIdx.y;
  const int f0 = w * 64;

  for (int idx = tid; idx < 78 * 16; idx += 256) {
    int rr = idx >> 4, c = (idx & 15) * 4;
    int g = f0 - 7 + rr;
    float4 kv = {0.f, 0.f, 0.f, 0.f}, vv = {0.f, 0.f, 0.f, 0.f};
    if (g >= 0 && g < 4096) {
      size_t base = ((size_t)n * 4096 + g) * 64 + c;
      kv = *(const float4*)(Kb + base);
      vv = *(const float4*)(Vb + base);
    }
    *(float4*)&Ks[rr][c] = kv;
    *(float4*)&Vs[rr][c] = vv;
  }
  __syncthreads();

  const int i = tid >> 2, q = tid & 3;
  const int f = f0 + i;
  const size_t qbase = ((size_t)n * 4096 + f) * 64 + q * 16;
  float4 q0 = *(const float4*)(Qb + qbase);
  float4 q1 = *(const float4*)(Qb + qbase + 4);
  float4 q2 = *(const float4*)(Qb + qbase + 8);
  float4 q3 = *(const float4*)(Qb + qbase + 12);
  float4 e0 = *(const float4*)(ex + qbase);
  float4 e1 = *(const float4*)(ex + qbase + 4);
  float4 e2 = *(const float4*)(ex + qbase + 8);
  float4 e3 = *(const float4*)(ex + qbase + 12);

  float s0 = q0.x * e0.x + q0.y * e0.y + q0.z * e0.z + q0.w * e0.w +
             q1.x * e1.x + q1.y * e1.y + q1.z * e1.z + q1.w * e1.w +
             q2.x * e2.x + q2.y * e2.y + q2.z * e2.z + q2.w * e2.w +
             q3.x * e3.x + q3.y * e3.y + q3.z * e3.z + q3.w * e3.w;
  s0 += __shfl_xor(s0, 1);
  s0 += __shfl_xor(s0, 2);

  float sj[15];
#pragma unroll
  for (int j = 0; j < 15; ++j) {
    const float* kr = &Ks[i + j][q * 16];
    float4 k0 = *(const float4*)(kr);
    float4 k1 = *(const float4*)(kr + 4);
    float4 k2 = *(const float4*)(kr + 8);
    float4 k3 = *(const float4*)(kr + 12);
    float s = q0.x * k0.x + q0.y * k0.y + q0.z * k0.z + q0.w * k0.w +
              q1.x * k1.x + q1.y * k1.y + q1.z * k1.z + q1.w * k1.w +
              q2.x * k2.x + q2.y * k2.y + q2.z * k2.z + q2.w * k2.w +
              q3.x * k3.x + q3.y * k3.y + q3.z * k3.z + q3.w * k3.w;
    s += __shfl_xor(s, 1);
    s += __shfl_xor(s, 2);
    sj[j] = s;
  }

  if (q == 0) s0s[i] = s0;
  __syncthreads();
  if (tid < 64) {
    float v = s0s[tid];
    float m = v;
    for (int o = 1; o < 64; o <<= 1) m = fmaxf(m, __shfl_xor(m, o));
    float ee = expf(v - m);
    float s = ee;
    for (int o = 1; o < 64; o <<= 1) s += __shfl_xor(s, o);
    if (tid == 0) { red[0] = m; red[1] = s; }
  }
  __syncthreads();
  const float wt = expf(s0 - red[0]) / red[1];

  float mx = sj[0];
#pragma unroll
  for (int j = 1; j < 15; ++j) mx = fmaxf(mx, sj[j]);
  float pj[15], den = 0.f;
#pragma unroll
  for (int j = 0; j < 15; ++j) { pj[j] = expf(sj[j] - mx); den += pj[j]; }
  const float inv = 1.0f / den;

  float o[16] = {wt * e0.x, wt * e0.y, wt * e0.z, wt * e0.w,
                 wt * e1.x, wt * e1.y, wt * e1.z, wt * e1.w,
                 wt * e2.x, wt * e2.y, wt * e2.z, wt * e2.w,
                 wt * e3.x, wt * e3.y, wt * e3.z, wt * e3.w};
#pragma unroll
  for (int j = 0; j < 15; ++j) {
    float wj = pj[j] * inv;
    const float* vr = &Vs[i + j][q * 16];
#pragma unroll
    for (int dd = 0; dd < 16; ++dd) o[dd] = fmaf(wj, vr[dd], o[dd]);
  }
  _Float16 oh[16], ol[16];
#pragma unroll
  for (int dd = 0; dd < 16; ++dd) {
    _Float16 hh = (_Float16)o[dd];
    oh[dd] = hh;
    ol[dd] = (_Float16)(o[dd] - (float)hh);
  }
  *(float4*)(OFh + qbase) = *(float4*)&oh[0];
  *(float4*)(OFh + qbase + 8) = *(float4*)&oh[8];
  *(float4*)(OFl + qbase) = *(float4*)&ol[0];
  *(float4*)(OFl + qbase + 8) = *(float4*)&ol[8];
}

// ---------------------------------------------------------------- K4: out proj
// MFMA f16x3. M=16640 (4x4160, word-token rows from x, frame rows from OF),
// N=256, K=256.
__global__ __launch_bounds__(256) void out_mfma(
    const _Float16* __restrict__ xh, const _Float16* __restrict__ xl,
    const _Float16* __restrict__ ofh, const _Float16* __restrict__ ofl,
    const _Float16* __restrict__ wth, const _Float16* __restrict__ wtl,
    const float* __restrict__ bo, float* __restrict__ out) {
  __shared__ _Float16 Ah[128][40];
  __shared__ _Float16 Al[128][40];
  const int tid = threadIdx.x;
  const int wave = tid >> 6, lane = tid & 63;
  const int ln = lane & 31, half = lane >> 5;
  const int mw = (wave & 1) * 64, nw = (wave >> 1) * 32;
  const int m0 = blockIdx.x * 128, n0 = blockIdx.y * 64;

  const int r = tid >> 1, seg = tid & 1;
  const int m = m0 + r;
  const int b = m / 4160, t = m % 4160;
  const bool useX = (t < 64);
  const size_t xoff = ((size_t)(b * 4160 + t)) * 256 + seg * 16;

  const _Float16* wp_h = wth + (size_t)(n0 + nw + ln) * 256 + half * 8;
  const _Float16* wp_l = wtl + (size_t)(n0 + nw + ln) * 256 + half * 8;

  f32x16 acc0 = {}, acc1 = {};

  for (int k0 = 0; k0 < 256; k0 += 32) {
    size_t off;
    const _Float16 *sh, *sl;
    if (useX) {
      sh = xh; sl = xl; off = xoff + k0;
    } else {
      int hh = k0 >> 6;
      sh = ofh; sl = ofl;
      off = (((size_t)(b * 4 + hh)) * 4096 + (t - 64)) * 64 + (k0 & 63) + seg * 16;
    }
    float4 gh0 = *(const float4*)(sh + off);
    float4 gh1 = *(const float4*)(sh + off + 8);
    float4 gl0 = *(const float4*)(sl + off);
    float4 gl1 = *(const float4*)(sl + off + 8);
    h8 bh0 = *(const h8*)(wp_h + k0);
    h8 bh1 = *(const h8*)(wp_h + k0 + 16);
    h8 bl0 = *(const h8*)(wp_l + k0);
    h8 bl1 = *(const h8*)(wp_l + k0 + 16);
    __syncthreads();
    *(float4*)&Ah[r][seg * 16] = gh0;
    *(float4*)&Ah[r][seg * 16 + 8] = gh1;
    *(float4*)&Al[r][seg * 16] = gl0;
    *(float4*)&Al[r][seg * 16 + 8] = gl1;
    __syncthreads();
#pragma unroll
    for (int ks = 0; ks < 2; ++ks) {
      const int kc = ks * 16 + half * 8;
      h8 a0h = *(const h8*)&Ah[mw + ln][kc];
      h8 a0l = *(const h8*)&Al[mw + ln][kc];
      h8 a1h = *(const h8*)&Ah[mw + 32 + ln][kc];
      h8 a1l = *(const h8*)&Al[mw + 32 + ln][kc];
      h8 bh = ks ? bh1 : bh0;
      h8 bl = ks ? bl1 : bl0;
      acc0 = __builtin_amdgcn_mfma_f32_32x32x16_f16(a0h, bh, acc0, 0, 0, 0);
      acc1 = __builtin_amdgcn_mfma_f32_32x32x16_f16(a1h, bh, acc1, 0, 0, 0);
      acc0 = __builtin_amdgcn_mfma_f32_32x32x16_f16(a0h, bl, acc0, 0, 0, 0);
      acc1 = __builtin_amdgcn_mfma_f32_32x32x16_f16(a1h, bl, acc1, 0, 0, 0);
      acc0 = __builtin_amdgcn_mfma_f32_32x32x16_f16(a0l, bh, acc0, 0, 0, 0);
      acc1 = __builtin_amdgcn_mfma_f32_32x32x16_f16(a1l, bh, acc1, 0, 0, 0);
    }
  }

  const int c = n0 + nw + ln;
  const float bias = bo[c];
#pragma unroll
  for (int t2 = 0; t2 < 2; ++t2) {
    const int rb = m0 + mw + t2 * 32 + 4 * half;
#pragma unroll
    for (int reg = 0; reg < 16; ++reg) {
      float av = t2 ? acc1[reg] : acc0[reg];
      int rr = rb + (reg & 3) + 8 * (reg >> 2);
      out[(size_t)rr * 256 + c] = av + bias;
    }
  }
}

// ---------------------------------------------------------------- launch
extern "C" void kernel_launch(void* const* d_in, const int* in_sizes, int n_in,
                              void* d_out, int out_size, void* d_ws, size_t ws_size,
                              hipStream_t stream) {
  const float* x  = (const float*)d_in[0];
  const float* wm = (const float*)d_in[1];
  const float* Wq = (const float*)d_in[2];
  const float* bq = (const float*)d_in[3];
  const float* Wo = (const float*)d_in[4];
  const float* bo = (const float*)d_in[5];
  float* out = (float*)d_out;

  float* Qb = (float*)d_ws;
  float* Kb = Qb + QN;
  float* Vb = Kb + QN;
  float* EX = Vb + QN;
  _Float16* xh   = (_Float16*)(EX + QN);
  _Float16* xl   = xh + XN;
  _Float16* OFh  = xl + XN;
  _Float16* OFl  = OFh + QN;
  _Float16* Wqth = OFl + QN;       // [768][256]
  _Float16* Wqtl = Wqth + 196608;
  _Float16* Woth = Wqtl + 196608;  // [256][256]
  _Float16* Wotl = Woth + 65536;
  // total ~102 MB of workspace

  conv_x<<<dim3(XN / 4 / 256), 256, 0, stream>>>(x, xh, xl);
  conv_wT<<<dim3(768), 256, 0, stream>>>(Wq, Wqth, Wqtl, 768);
  conv_wT<<<dim3(256), 256, 0, stream>>>(Wo, Woth, Wotl, 256);
  qkv_mfma<<<dim3(128, 12), 256, 0, stream>>>(xh, xl, Wqth, Wqtl, bq, Qb, Kb, Vb);
  expa_kernel<<<dim3(64, 16), 256, 0, stream>>>(x, wm, EX);
  attn_kernel<<<dim3(64, 16), 256, 0, stream>>>(Qb, Kb, Vb, EX, OFh, OFl);
  out_mfma<<<dim3(130, 4), 256, 0, stream>>>(xh, xl, OFh, OFl, Woth, Wotl, bo, out);
}